// Round 7
// baseline (89.606 us; speedup 1.0000x reference)
//
#include <hip/hip_runtime.h>
#include <hip/hip_bf16.h>
#include <hip/hip_fp16.h>

#define NB      8
#define NPTS    4096
#define KSEL    16
#define HSZ     4            // per-wave-slice list size (16-way split, exact slice top-4)
#define THREADS 1024
#define WV      16           // waves per block = candidate slices
#define CHUNK   (NPTS/WV)    // 256 candidates per wave per array
#define PAIRS   (CHUNK/2)    // 128 packed pairs per wave per array
#define NSLOTS  64
#define HALF    (NB*NPTS)    // 32768 points per array
#define HPAIR   (HALF/2)     // packed pairs per array

typedef _Float16 h2 __attribute__((ext_vector_type(2)));

__device__ __forceinline__ h2 h2min(h2 a, h2 b) { return __builtin_elementwise_min(a, b); }
__device__ __forceinline__ h2 h2max(h2 a, h2 b) { return __builtin_elementwise_max(a, b); }
__device__ __forceinline__ h2 h2fma(h2 a, h2 b, h2 c) { return __builtin_elementwise_fma(a, b, c); }

__device__ __forceinline__ void ce(float& a, float& b) {
  const float lo = fminf(a, b), hi = fmaxf(a, b);
  a = lo; b = hi;
}

// Packed sorted-asc top-4 insert (each half = independent list):
// med3(d,h[j-1],h[j]) == min(max(d,h[j-1]), h[j]) since h sorted asc. All reads old.
__device__ __forceinline__ void insert4p(h2* h, h2 d) {
  h[3] = h2min(h2max(d, h[2]), h[3]);
  h[2] = h2min(h2max(d, h[1]), h[2]);
  h[1] = h2min(h2max(d, h[0]), h[1]);
  h[0] = h2min(h[0], d);
}

// In-place grow-merge: h[0..N) sorted asc + g[0..N) sorted asc -> h[0..2N) sorted.
template<int N>
__device__ __forceinline__ void grow_ip(float* h, const float* g) {
#pragma unroll
  for (int i = 0; i < N; ++i) h[2 * N - 1 - i] = g[i];
#pragma unroll
  for (int d = N; d >= 1; d >>= 1)
#pragma unroll
    for (int i = 0; i < 2 * N; ++i)
      if ((i & d) == 0) ce(h[i], h[i + d]);
}

// In-place keep-16 merge of two sorted-16 lists.
__device__ __forceinline__ void keep16(float* h, const float* g) {
#pragma unroll
  for (int i = 0; i < KSEL; ++i) h[i] = fminf(h[i], g[KSEL - 1 - i]);
#pragma unroll
  for (int d = 8; d >= 1; d >>= 1)
#pragma unroll
    for (int i = 0; i < KSEL; ++i)
      if ((i & d) == 0) ce(h[i], h[i + d]);
}

// Pack candidate PAIRS as f16 SoA: uint4{ h2(x0,x1), h2(y0,y1), h2(z0,z1), 0 }.
extern "C" __global__ __launch_bounds__(256)
void prep_kernel(const float* __restrict__ gts, const float* __restrict__ preds,
                 uint4* __restrict__ pk) {
  const int i = blockIdx.x * 256 + threadIdx.x;     // pair index, 0..HALF-1
  const float* __restrict__ src = (i < HPAIR) ? preds : gts;
  const int j = (i < HPAIR) ? i : i - HPAIR;        // pair within array
  const float* p0 = src + 6 * j;                    // elements 2j, 2j+1
  const h2 hx = { (_Float16)p0[0], (_Float16)p0[3] };
  const h2 hy = { (_Float16)p0[1], (_Float16)p0[4] };
  const h2 hz = { (_Float16)p0[2], (_Float16)p0[5] };
  uint4 o;
  o.x = __builtin_bit_cast(unsigned, hx);
  o.y = __builtin_bit_cast(unsigned, hy);
  o.z = __builtin_bit_cast(unsigned, hz);
  o.w = 0u;
  pk[i] = o;
}

extern "C" __global__ void init_acc(double* acc) {
  const int t = threadIdx.x;
  if (t < 3 * NSLOTS) acc[t] = 0.0;
}

// lane = query point (64/block), wave = candidate-sixteenth (scalar-broadcast stream).
// Hot loop: s_load uint4 = 2 candidates; all math VOP3P packed f16; no LDS/cross-lane.
extern "C" __global__ __launch_bounds__(THREADS, 8)
void fused_kernel(const float* __restrict__ gts, const float* __restrict__ preds,
                  const uint4* __restrict__ pk, double* __restrict__ acc) {
  __shared__ float B1[2048];
  __shared__ float B2[2048];
  __shared__ float BB[512];

  const int t    = threadIdx.x;
  const int lane = t & 63;
  const int w    = __builtin_amdgcn_readfirstlane(t >> 6);  // wave id, uniform
  const int b    = blockIdx.y;
  const int pt   = blockIdx.x * 64 + lane;

  const float* __restrict__ gq = gts + ((size_t)b * NPTS + pt) * 3;
  const float qxf = gq[0], qyf = gq[1], qzf = gq[2];
  const float* __restrict__ pq = preds + ((size_t)b * NPTS + pt) * 3;
  const float pxf = pq[0], pyf = pq[1], pzf = pq[2];
  const h2 qx = { (_Float16)qxf, (_Float16)qxf };
  const h2 qy = { (_Float16)qyf, (_Float16)qyf };
  const h2 qz = { (_Float16)qzf, (_Float16)qzf };
  const h2 px = { (_Float16)pxf, (_Float16)pxf };
  const h2 py = { (_Float16)pyf, (_Float16)pyf };
  const h2 pz = { (_Float16)pzf, (_Float16)pzf };

  const h2 big = { (_Float16)65504.0f, (_Float16)65504.0f };
  h2 h1p[HSZ], h2p[HSZ];
#pragma unroll
  for (int i = 0; i < HSZ; ++i) { h1p[i] = big; h2p[i] = big; }
  h2 bwp = big;

  const uint4* __restrict__ cp = pk + (size_t)b * (NPTS / 2) + w * PAIRS;          // preds
  const uint4* __restrict__ cg = pk + HPAIR + (size_t)b * (NPTS / 2) + w * PAIRS;  // gts

#pragma unroll 4
  for (int j = 0; j < PAIRS; ++j) {
    const uint4 c = cp[j];                          // SGPR broadcast (s_load dwordx4)
    const h2 cx = __builtin_bit_cast(h2, c.x);
    const h2 cy = __builtin_bit_cast(h2, c.y);
    const h2 cz = __builtin_bit_cast(h2, c.z);
    const h2 dx = qx - cx, dy = qy - cy, dz = qz - cz;
    h2 s = dx * dx;
    s = h2fma(dy, dy, s);
    s = h2fma(dz, dz, s);
    insert4p(h1p, s);
  }

#pragma unroll 4
  for (int j = 0; j < PAIRS; ++j) {
    const uint4 c = cg[j];
    const h2 cx = __builtin_bit_cast(h2, c.x);
    const h2 cy = __builtin_bit_cast(h2, c.y);
    const h2 cz = __builtin_bit_cast(h2, c.z);
    const h2 dx = qx - cx, dy = qy - cy, dz = qz - cz;
    h2 s = dx * dx;
    s = h2fma(dy, dy, s);
    s = h2fma(dz, dz, s);
    insert4p(h2p, s);
    const h2 ex = px - cx, ey = py - cy, ez = pz - cz;
    h2 u = ex * ex;
    u = h2fma(ey, ey, u);
    u = h2fma(ez, ez, u);
    bwp = h2min(bwp, u);                            // loss_1 partial (query = pred pt)
  }

  // Unpack: lo/hi halves are two sorted-4 lists; merge -> exact slice top-4 in f1/f2[0..4).
  float f1[KSEL], f2[KSEL], g4[HSZ];
#pragma unroll
  for (int i = 0; i < HSZ; ++i) { f1[i] = (float)h1p[i][0]; g4[i] = (float)h1p[i][1]; }
  grow_ip<HSZ>(f1, g4);                             // f1[0..8) sorted; keep [0..4)
#pragma unroll
  for (int i = 0; i < HSZ; ++i) { f2[i] = (float)h2p[i][0]; g4[i] = (float)h2p[i][1]; }
  grow_ip<HSZ>(f2, g4);
  float bw = fminf((float)bwp[0], (float)bwp[1]);

  // ---- 4-level cross-wave merge tree: 16 -> 8 -> 4 -> 2 -> 1 ----------------
  if (w >= 8) {
    const int s = w - 8;
    float* p1 = &B1[(s * 64 + lane) * HSZ];
    float* p2 = &B2[(s * 64 + lane) * HSZ];
#pragma unroll
    for (int i = 0; i < HSZ; ++i) { p1[i] = f1[i]; p2[i] = f2[i]; }
    BB[s * 64 + lane] = bw;
  }
  __syncthreads();
  if (w < 8) {
    grow_ip<4>(f1, &B1[(w * 64 + lane) * HSZ]);
    grow_ip<4>(f2, &B2[(w * 64 + lane) * HSZ]);
    bw = fminf(bw, BB[w * 64 + lane]);
  }
  __syncthreads();
  if (w >= 4 && w < 8) {
    const int s = w - 4;
    float* p1 = &B1[(s * 64 + lane) * 8];
    float* p2 = &B2[(s * 64 + lane) * 8];
#pragma unroll
    for (int i = 0; i < 8; ++i) { p1[i] = f1[i]; p2[i] = f2[i]; }
    BB[s * 64 + lane] = bw;
  }
  __syncthreads();
  if (w < 4) {
    grow_ip<8>(f1, &B1[(w * 64 + lane) * 8]);
    grow_ip<8>(f2, &B2[(w * 64 + lane) * 8]);
    bw = fminf(bw, BB[w * 64 + lane]);
  }
  __syncthreads();
  if (w == 2 || w == 3) {
    const int s = w - 2;
    float* p1 = &B1[(s * 64 + lane) * KSEL];
    float* p2 = &B2[(s * 64 + lane) * KSEL];
#pragma unroll
    for (int i = 0; i < KSEL; ++i) { p1[i] = f1[i]; p2[i] = f2[i]; }
    BB[s * 64 + lane] = bw;
  }
  __syncthreads();
  if (w < 2) {
    keep16(f1, &B1[(w * 64 + lane) * KSEL]);
    keep16(f2, &B2[(w * 64 + lane) * KSEL]);
    bw = fminf(bw, BB[w * 64 + lane]);
  }
  __syncthreads();
  if (w == 1) {
    float* p1 = &B1[lane * KSEL];
    float* p2 = &B2[lane * KSEL];
#pragma unroll
    for (int i = 0; i < KSEL; ++i) { p1[i] = f1[i]; p2[i] = f2[i]; }
    BB[lane] = bw;
  }
  __syncthreads();
  if (w == 0) {
    keep16(f1, &B1[lane * KSEL]);
    keep16(f2, &B2[lane * KSEL]);
    bw = fminf(bw, BB[lane]);

    float v1 = bw;            // loss_1 term (pred point pt) — full dist, no norm fixup
    float v2 = f1[0];         // loss_2 term (gt point pt)
    float v3 = 0.0f;          // density
#pragma unroll
    for (int i = 0; i < KSEL; ++i) {
      const float df = f1[i] - f2[i];
      v3 = fmaf(df, df, v3);
    }
#pragma unroll
    for (int off = 32; off >= 1; off >>= 1) {
      v1 += __shfl_xor(v1, off);
      v2 += __shfl_xor(v2, off);
      v3 += __shfl_xor(v3, off);
    }
    if (lane == 0) {
      const int slot = (blockIdx.x + 13 * blockIdx.y) & (NSLOTS - 1);
      atomicAdd(&acc[0 * NSLOTS + slot], (double)v1);
      atomicAdd(&acc[1 * NSLOTS + slot], (double)v2);
      atomicAdd(&acc[2 * NSLOTS + slot], (double)v3);
    }
  }
}

extern "C" __global__ void finalize_kernel(const double* __restrict__ acc,
                                           float* __restrict__ out) {
  const int l = threadIdx.x;  // 64 threads
  double a = acc[l], b = acc[NSLOTS + l], c = acc[2 * NSLOTS + l];
#pragma unroll
  for (int off = 32; off >= 1; off >>= 1) {
    a += __shfl_xor(a, off);
    b += __shfl_xor(b, off);
    c += __shfl_xor(c, off);
  }
  if (l == 0) {
    const double loss1 = a / (double)((size_t)NB * NPTS);
    const double loss2 = b / (double)((size_t)NB * NPTS);
    const double dens  = c / (double)((size_t)NB * NPTS * KSEL);
    out[0] = (float)(loss1 + loss2);
    out[1] = (float)dens;
  }
}

extern "C" void kernel_launch(void* const* d_in, const int* in_sizes, int n_in,
                              void* d_out, int out_size, void* d_ws, size_t ws_size,
                              hipStream_t stream) {
  const float* gts   = (const float*)d_in[0];
  const float* preds = (const float*)d_in[1];
  uint4*  pk  = (uint4*)d_ws;                           // HALF uint4 = 512 KiB
  double* acc = (double*)((char*)d_ws + (size_t)HALF * sizeof(uint4));
  float*  out = (float*)d_out;

  hipLaunchKernelGGL(prep_kernel, dim3(HALF / 256), dim3(256), 0, stream,
                     gts, preds, pk);
  hipLaunchKernelGGL(init_acc, dim3(1), dim3(256), 0, stream, acc);
  hipLaunchKernelGGL(fused_kernel, dim3(NPTS / 64, NB), dim3(THREADS), 0, stream,
                     gts, preds, pk, acc);
  hipLaunchKernelGGL(finalize_kernel, dim3(1), dim3(64), 0, stream, acc, out);
}

// Round 8
// 71.887 us; speedup vs baseline: 1.2465x; 1.2465x over previous
//
#include <hip/hip_runtime.h>
#include <hip/hip_bf16.h>
#include <hip/hip_fp16.h>

#define NB      8
#define NPTS    4096
#define KSEL    16
#define THREADS 512
#define CW      8            // candidate-split waves per block
#define TPW     16           // tiles per wave = NPTS/(CW*32)
#define NSLOTS  64
#define HALFPTS (NB*NPTS)    // 32768 points per array

typedef _Float16 f16x8 __attribute__((ext_vector_type(8)));
typedef float    f32x16 __attribute__((ext_vector_type(16)));

__device__ __forceinline__ void ce(float& a, float& b) {
  const float lo = fminf(a, b), hi = fmaxf(a, b);
  a = lo; b = hi;
}

// sorted-asc top-4 insert via med3 (reads old values only; 3 VOP3 + 1 VOP2).
__device__ __forceinline__ void insert4(float* h, float d) {
  h[3] = __builtin_amdgcn_fmed3f(d, h[2], h[3]);
  h[2] = __builtin_amdgcn_fmed3f(d, h[1], h[2]);
  h[1] = __builtin_amdgcn_fmed3f(d, h[0], h[1]);
  h[0] = fminf(h[0], d);
}

// o[0..8) = sorted union of sorted a[0..4), b[0..4)
__device__ __forceinline__ void m44(float* o, const float* a, const float* b) {
  o[0]=a[0]; o[1]=a[1]; o[2]=a[2]; o[3]=a[3];
  o[4]=b[3]; o[5]=b[2]; o[6]=b[1]; o[7]=b[0];
  ce(o[0],o[4]); ce(o[1],o[5]); ce(o[2],o[6]); ce(o[3],o[7]);
  ce(o[0],o[2]); ce(o[1],o[3]); ce(o[4],o[6]); ce(o[5],o[7]);
  ce(o[0],o[1]); ce(o[2],o[3]); ce(o[4],o[5]); ce(o[6],o[7]);
}

// o[0..16) = sorted union of sorted a[0..8), b[0..8)
__device__ __forceinline__ void m88(float* o, const float* a, const float* b) {
#pragma unroll
  for (int i = 0; i < 8; ++i) { o[i] = a[i]; o[15 - i] = b[i]; }
#pragma unroll
  for (int d = 8; d >= 1; d >>= 1)
#pragma unroll
    for (int i = 0; i < 16; ++i)
      if ((i & d) == 0) ce(o[i], o[i + d]);
}

// keep smallest-16 of two sorted-16 lists, in place in h.
__device__ __forceinline__ void keep16(float* h, const float* g) {
#pragma unroll
  for (int i = 0; i < KSEL; ++i) h[i] = fminf(h[i], g[KSEL - 1 - i]);
#pragma unroll
  for (int d = 8; d >= 1; d >>= 1)
#pragma unroll
    for (int i = 0; i < KSEL; ++i)
      if ((i & d) == 0) ce(h[i], h[i + d]);
}

// Per point: Q-role K-vector [xh,xh,xl, yh,yh,yl, zh,zh,zl, 1,1, 0...] and
// C-role [(-2x)h,(-2x)l,(-2x)h, ..., cnh,cnl, 0...]; dot(Q,C) = -2 q.c + |c|^2
// with ~1e-6 abs error (3-term hi/lo products, f32 MFMA accumulation).
extern "C" __global__ __launch_bounds__(256)
void prep_kernel(const float* __restrict__ gts, const float* __restrict__ preds,
                 _Float16* __restrict__ Qg, _Float16* __restrict__ Cg,
                 _Float16* __restrict__ Qp, _Float16* __restrict__ Cp) {
  const int i = blockIdx.x * 256 + threadIdx.x;     // 0..2*HALFPTS-1
  const bool isg = i < HALFPTS;
  const float* __restrict__ src = isg ? gts : preds;
  const int j = isg ? i : i - HALFPTS;
  const float x = src[3*j], y = src[3*j+1], z = src[3*j+2];
  const float cn = fmaf(x, x, fmaf(y, y, z * z));

  const _Float16 xh = (_Float16)x, yh = (_Float16)y, zh = (_Float16)z;
  const _Float16 xl = (_Float16)(x - (float)xh);
  const _Float16 yl = (_Float16)(y - (float)yh);
  const _Float16 zl = (_Float16)(z - (float)zh);
  const float mx = -2.f*x, my = -2.f*y, mz = -2.f*z;
  const _Float16 mxh = (_Float16)mx, myh = (_Float16)my, mzh = (_Float16)mz;
  const _Float16 mxl = (_Float16)(mx - (float)mxh);
  const _Float16 myl = (_Float16)(my - (float)myh);
  const _Float16 mzl = (_Float16)(mz - (float)mzh);
  const _Float16 cnh = (_Float16)cn;
  const _Float16 cnl = (_Float16)(cn - (float)cnh);
  const _Float16 one = (_Float16)1.0f, zr = (_Float16)0.0f;

  _Float16* Q = (isg ? Qg : Qp) + (size_t)j * 16;
  _Float16* C = (isg ? Cg : Cp) + (size_t)j * 16;
  Q[0]=xh; Q[1]=xh; Q[2]=xl; Q[3]=yh; Q[4]=yh; Q[5]=yl;
  Q[6]=zh; Q[7]=zh; Q[8]=zl; Q[9]=one; Q[10]=one;
  Q[11]=zr; Q[12]=zr; Q[13]=zr; Q[14]=zr; Q[15]=zr;
  C[0]=mxh; C[1]=mxl; C[2]=mxh; C[3]=myh; C[4]=myl; C[5]=myh;
  C[6]=mzh; C[7]=mzl; C[8]=mzh; C[9]=cnh; C[10]=cnl;
  C[11]=zr; C[12]=zr; C[13]=zr; C[14]=zr; C[15]=zr;
}

extern "C" __global__ void init_acc(double* acc) {
  const int t = threadIdx.x;
  if (t < 3 * NSLOTS) acc[t] = 0.0;
}

// Block: 8 waves share one 32-query strip; wave w owns candidate slice w (512 cands
// = 16 tiles of 32). MFMA(A=cand-frag, B=query-frag): C/D col=lane&31 -> this
// lane's query; rows = 16 cands per lane. Selection on VALU: 4 top-4 lists (A/B
// searches) or v_min chain (C). Merge: in-lane bitonic + shfl(32) + LDS tree.
extern "C" __global__ __launch_bounds__(THREADS, 4)
void fused_kernel(const float* __restrict__ gts, const float* __restrict__ preds,
                  const _Float16* __restrict__ Qg, const _Float16* __restrict__ Cg,
                  const _Float16* __restrict__ Qp, const _Float16* __restrict__ Cp,
                  double* __restrict__ acc) {
  __shared__ float T[4][32][KSEL + 1];   // +1 pad: stride 17 -> conflict-free
  __shared__ float TB[CW][32];

  const int t    = threadIdx.x;
  const int lane = t & 63;
  const int w    = t >> 6;
  const int col  = lane & 31;
  const int half = lane >> 5;
  const int b    = blockIdx.y;
  const int strip= blockIdx.x;

  const size_t qoff = ((size_t)(b * NPTS + strip * 32 + col)) * 16 + half * 8;
  const f16x8 qg = *(const f16x8*)(Qg + qoff);
  const f16x8 qp = *(const f16x8*)(Qp + qoff);
  f32x16 zz;
#pragma unroll
  for (int i = 0; i < 16; ++i) zz[i] = 0.f;

#define TREE16(f)                                                        \
  do {                                                                   \
    __syncthreads();                                                     \
    if (w >= 4 && half == 0) {                                           \
      _Pragma("unroll") for (int i = 0; i < KSEL; ++i) T[w-4][col][i] = (f)[i]; \
    }                                                                    \
    __syncthreads();                                                     \
    if (w < 4) { float g[KSEL];                                          \
      _Pragma("unroll") for (int i = 0; i < KSEL; ++i) g[i] = T[w][col][i]; \
      keep16((f), g); }                                                  \
    __syncthreads();                                                     \
    if ((w == 2 || w == 3) && half == 0) {                               \
      _Pragma("unroll") for (int i = 0; i < KSEL; ++i) T[w-2][col][i] = (f)[i]; \
    }                                                                    \
    __syncthreads();                                                     \
    if (w < 2) { float g[KSEL];                                          \
      _Pragma("unroll") for (int i = 0; i < KSEL; ++i) g[i] = T[w][col][i]; \
      keep16((f), g); }                                                  \
    __syncthreads();                                                     \
    if (w == 1 && half == 0) {                                           \
      _Pragma("unroll") for (int i = 0; i < KSEL; ++i) T[0][col][i] = (f)[i]; \
    }                                                                    \
    __syncthreads();                                                     \
    if (w == 0) { float g[KSEL];                                         \
      _Pragma("unroll") for (int i = 0; i < KSEL; ++i) g[i] = T[0][col][i]; \
      keep16((f), g); }                                                  \
  } while (0)

  // ---- Loop 2: cands = gts.  B-search (queries gts) + C-min (queries preds) ----
  float h2l[16];
#pragma unroll
  for (int i = 0; i < 16; ++i) h2l[i] = 1e30f;
  float bw = 1e30f;
  {
    const _Float16* cb = Cg + ((size_t)(b * NPTS + w * 512)) * 16;
#pragma unroll 2
    for (int tile = 0; tile < TPW; ++tile) {
      const f16x8 at = *(const f16x8*)(cb + (size_t)(tile * 32 + col) * 16 + half * 8);
      const f32x16 aB = __builtin_amdgcn_mfma_f32_32x32x16_f16(at, qg, zz, 0, 0, 0);
      const f32x16 aC = __builtin_amdgcn_mfma_f32_32x32x16_f16(at, qp, zz, 0, 0, 0);
#pragma unroll
      for (int r = 0; r < 16; ++r) {
        insert4(h2l + (r >> 2) * 4, aB[r]);
        bw = fminf(bw, aC[r]);
      }
    }
  }
  float f2[KSEL];
  {
    float e0[8], e1[8];
    m44(e0, h2l + 0, h2l + 4); m44(e1, h2l + 8, h2l + 12);
    m88(f2, e0, e1);
    float g[KSEL];
#pragma unroll
    for (int i = 0; i < KSEL; ++i) g[i] = __shfl_xor(f2[i], 32);
    keep16(f2, g);
    bw = fminf(bw, __shfl_xor(bw, 32));
  }
  // bw across waves
  if (half == 0) TB[w][col] = bw;
  TREE16(f2);            // f2 final in wave 0 (both halves)
  __syncthreads();
  if (w == 0) {
#pragma unroll
    for (int ww = 1; ww < CW; ++ww) bw = fminf(bw, TB[ww][col]);
  }

  // ---- Loop 1: cands = preds, queries = gts (A-search) ----
  float h1l[16];
#pragma unroll
  for (int i = 0; i < 16; ++i) h1l[i] = 1e30f;
  {
    const _Float16* cb = Cp + ((size_t)(b * NPTS + w * 512)) * 16;
#pragma unroll 2
    for (int tile = 0; tile < TPW; ++tile) {
      const f16x8 at = *(const f16x8*)(cb + (size_t)(tile * 32 + col) * 16 + half * 8);
      const f32x16 aA = __builtin_amdgcn_mfma_f32_32x32x16_f16(at, qg, zz, 0, 0, 0);
#pragma unroll
      for (int r = 0; r < 16; ++r) insert4(h1l + (r >> 2) * 4, aA[r]);
    }
  }
  float f1[KSEL];
  {
    float e0[8], e1[8];
    m44(e0, h1l + 0, h1l + 4); m44(e1, h1l + 8, h1l + 12);
    m88(f1, e0, e1);
    float g[KSEL];
#pragma unroll
    for (int i = 0; i < KSEL; ++i) g[i] = __shfl_xor(f1[i], 32);
    keep16(f1, g);
  }
  TREE16(f1);            // f1 final in wave 0

  // ---- epilogue (wave 0): re-add query norms, accumulate ----
  if (w == 0) {
    const float* gq = gts   + ((size_t)(b * NPTS) + strip * 32 + col) * 3;
    const float qn = fmaf(gq[0], gq[0], fmaf(gq[1], gq[1], gq[2] * gq[2]));
    const float* pq = preds + ((size_t)(b * NPTS) + strip * 32 + col) * 3;
    const float pn = fmaf(pq[0], pq[0], fmaf(pq[1], pq[1], pq[2] * pq[2]));

    float v1 = bw + pn;         // loss_1 term (pred query)
    float v2 = f1[0] + qn;      // loss_2 term (gt query)
    float v3 = 0.0f;            // density (qn cancels exactly)
#pragma unroll
    for (int i = 0; i < KSEL; ++i) {
      const float df = f1[i] - f2[i];
      v3 = fmaf(df, df, v3);
    }
    if (half) { v1 = 0.f; v2 = 0.f; v3 = 0.f; }   // halves are duplicates
#pragma unroll
    for (int off = 32; off >= 1; off >>= 1) {
      v1 += __shfl_xor(v1, off);
      v2 += __shfl_xor(v2, off);
      v3 += __shfl_xor(v3, off);
    }
    if (lane == 0) {
      const int slot = (strip + 13 * b) & (NSLOTS - 1);
      atomicAdd(&acc[0 * NSLOTS + slot], (double)v1);
      atomicAdd(&acc[1 * NSLOTS + slot], (double)v2);
      atomicAdd(&acc[2 * NSLOTS + slot], (double)v3);
    }
  }
#undef TREE16
}

extern "C" __global__ void finalize_kernel(const double* __restrict__ acc,
                                           float* __restrict__ out) {
  const int l = threadIdx.x;  // 64 threads
  double a = acc[l], b = acc[NSLOTS + l], c = acc[2 * NSLOTS + l];
#pragma unroll
  for (int off = 32; off >= 1; off >>= 1) {
    a += __shfl_xor(a, off);
    b += __shfl_xor(b, off);
    c += __shfl_xor(c, off);
  }
  if (l == 0) {
    const double loss1 = a / (double)((size_t)NB * NPTS);
    const double loss2 = b / (double)((size_t)NB * NPTS);
    const double dens  = c / (double)((size_t)NB * NPTS * KSEL);
    out[0] = (float)(loss1 + loss2);
    out[1] = (float)dens;
  }
}

extern "C" void kernel_launch(void* const* d_in, const int* in_sizes, int n_in,
                              void* d_out, int out_size, void* d_ws, size_t ws_size,
                              hipStream_t stream) {
  const float* gts   = (const float*)d_in[0];
  const float* preds = (const float*)d_in[1];
  char* ws = (char*)d_ws;
  const size_t ARR = (size_t)HALFPTS * 16 * sizeof(_Float16);   // 1 MiB each
  _Float16* Qg = (_Float16*)(ws + 0 * ARR);
  _Float16* Cg = (_Float16*)(ws + 1 * ARR);
  _Float16* Qp = (_Float16*)(ws + 2 * ARR);
  _Float16* Cp = (_Float16*)(ws + 3 * ARR);
  double*  acc = (double*)(ws + 4 * ARR);
  float*   out = (float*)d_out;

  hipLaunchKernelGGL(prep_kernel, dim3(2 * HALFPTS / 256), dim3(256), 0, stream,
                     gts, preds, Qg, Cg, Qp, Cp);
  hipLaunchKernelGGL(init_acc, dim3(1), dim3(256), 0, stream, acc);
  hipLaunchKernelGGL(fused_kernel, dim3(NPTS / 32, NB), dim3(THREADS), 0, stream,
                     gts, preds, Qg, Cg, Qp, Cp, acc);
  hipLaunchKernelGGL(finalize_kernel, dim3(1), dim3(64), 0, stream, acc, out);
}

// Round 9
// 59.530 us; speedup vs baseline: 1.5052x; 1.2076x over previous
//
#include <hip/hip_runtime.h>
#include <hip/hip_bf16.h>
#include <hip/hip_fp16.h>

#define NB      8
#define NPTS    4096
#define KSEL    16
#define THREADS 512
#define CW      8            // candidate-split waves per block
#define TPW     16           // tiles per wave = NPTS/(CW*32)
#define NSLOTS  64
#define HALFPTS (NB*NPTS)    // 32768 points per array

typedef _Float16 f16x8 __attribute__((ext_vector_type(8)));
typedef float    f32x16 __attribute__((ext_vector_type(16)));

__device__ __forceinline__ void ce(float& a, float& b) {
  const float lo = fminf(a, b), hi = fmaxf(a, b);
  a = lo; b = hi;
}
__device__ __forceinline__ float min3f(float a, float b, float c) {
  return fminf(fminf(a, b), c);              // fuses to v_min3_f32
}

// sorted-asc top-2 insert: 1 med3 + 1 min, reads old values only.
__device__ __forceinline__ void insert2(float* h, float d) {
  h[1] = __builtin_amdgcn_fmed3f(d, h[0], h[1]);
  h[0] = fminf(h[0], d);
}

// two sorted-2 -> sorted-4 (bitonic, 4 ce)
__device__ __forceinline__ void m22(float* o, const float* a, const float* b) {
  o[0]=a[0]; o[1]=a[1]; o[2]=b[1]; o[3]=b[0];
  ce(o[0],o[2]); ce(o[1],o[3]);
  ce(o[0],o[1]); ce(o[2],o[3]);
}

// two sorted-4 -> sorted-8 (12 ce)
__device__ __forceinline__ void m44(float* o, const float* a, const float* b) {
  o[0]=a[0]; o[1]=a[1]; o[2]=a[2]; o[3]=a[3];
  o[4]=b[3]; o[5]=b[2]; o[6]=b[1]; o[7]=b[0];
  ce(o[0],o[4]); ce(o[1],o[5]); ce(o[2],o[6]); ce(o[3],o[7]);
  ce(o[0],o[2]); ce(o[1],o[3]); ce(o[4],o[6]); ce(o[5],o[7]);
  ce(o[0],o[1]); ce(o[2],o[3]); ce(o[4],o[5]); ce(o[6],o[7]);
}

// two sorted-8 -> sorted-16 (32 ce)
__device__ __forceinline__ void m88(float* o, const float* a, const float* b) {
#pragma unroll
  for (int i = 0; i < 8; ++i) { o[i] = a[i]; o[15 - i] = b[i]; }
#pragma unroll
  for (int d = 8; d >= 1; d >>= 1)
#pragma unroll
    for (int i = 0; i < 16; ++i)
      if ((i & d) == 0) ce(o[i], o[i + d]);
}

// 8 sorted-2 lists (h[16]) -> sorted-16
__device__ __forceinline__ void sort8x2(float* f, const float* h) {
  float s0[4], s1[4], s2[4], s3[4];
  m22(s0, h + 0, h + 2);  m22(s1, h + 4,  h + 6);
  m22(s2, h + 8, h + 10); m22(s3, h + 12, h + 14);
  float e0[8], e1[8];
  m44(e0, s0, s1); m44(e1, s2, s3);
  m88(f, e0, e1);
}

// keep smallest-16 of two sorted-16 lists, in place in h.
__device__ __forceinline__ void keep16(float* h, const float* g) {
#pragma unroll
  for (int i = 0; i < KSEL; ++i) h[i] = fminf(h[i], g[KSEL - 1 - i]);
#pragma unroll
  for (int d = 8; d >= 1; d >>= 1)
#pragma unroll
    for (int i = 0; i < KSEL; ++i)
      if ((i & d) == 0) ce(h[i], h[i + d]);
}

// Per point: Q-role K-vector [xh,xh,xl, yh,yh,yl, zh,zh,zl, 1,1, 0...] and
// C-role [(-2x)h,(-2x)l,(-2x)h, ..., cnh,cnl, 0...]; dot(Q,C) = -2 q.c + |c|^2
// with ~1e-6 abs error (3-term hi/lo products, f32 MFMA accumulation).
extern "C" __global__ __launch_bounds__(256)
void prep_kernel(const float* __restrict__ gts, const float* __restrict__ preds,
                 _Float16* __restrict__ Qg, _Float16* __restrict__ Cg,
                 _Float16* __restrict__ Qp, _Float16* __restrict__ Cp) {
  const int i = blockIdx.x * 256 + threadIdx.x;     // 0..2*HALFPTS-1
  const bool isg = i < HALFPTS;
  const float* __restrict__ src = isg ? gts : preds;
  const int j = isg ? i : i - HALFPTS;
  const float x = src[3*j], y = src[3*j+1], z = src[3*j+2];
  const float cn = fmaf(x, x, fmaf(y, y, z * z));

  const _Float16 xh = (_Float16)x, yh = (_Float16)y, zh = (_Float16)z;
  const _Float16 xl = (_Float16)(x - (float)xh);
  const _Float16 yl = (_Float16)(y - (float)yh);
  const _Float16 zl = (_Float16)(z - (float)zh);
  const float mx = -2.f*x, my = -2.f*y, mz = -2.f*z;
  const _Float16 mxh = (_Float16)mx, myh = (_Float16)my, mzh = (_Float16)mz;
  const _Float16 mxl = (_Float16)(mx - (float)mxh);
  const _Float16 myl = (_Float16)(my - (float)myh);
  const _Float16 mzl = (_Float16)(mz - (float)mzh);
  const _Float16 cnh = (_Float16)cn;
  const _Float16 cnl = (_Float16)(cn - (float)cnh);
  const _Float16 one = (_Float16)1.0f, zr = (_Float16)0.0f;

  _Float16* Q = (isg ? Qg : Qp) + (size_t)j * 16;
  _Float16* C = (isg ? Cg : Cp) + (size_t)j * 16;
  Q[0]=xh; Q[1]=xh; Q[2]=xl; Q[3]=yh; Q[4]=yh; Q[5]=yl;
  Q[6]=zh; Q[7]=zh; Q[8]=zl; Q[9]=one; Q[10]=one;
  Q[11]=zr; Q[12]=zr; Q[13]=zr; Q[14]=zr; Q[15]=zr;
  C[0]=mxh; C[1]=mxl; C[2]=mxh; C[3]=myh; C[4]=myl; C[5]=myh;
  C[6]=mzh; C[7]=mzl; C[8]=mzh; C[9]=cnh; C[10]=cnl;
  C[11]=zr; C[12]=zr; C[13]=zr; C[14]=zr; C[15]=zr;
}

extern "C" __global__ void init_acc(double* acc) {
  const int t = threadIdx.x;
  if (t < 3 * NSLOTS) acc[t] = 0.0;
}

// Block: 8 waves share one 32-query strip; wave w owns candidate slice w (512 cands
// = 16 tiles of 32). MFMA scores; VALU selection = 8 top-2 lists (2 ops/score)
// + min3-tree for loss_1. Merge: in-lane bitonic + shfl(32) + LDS tree.
extern "C" __global__ __launch_bounds__(THREADS, 4)
void fused_kernel(const float* __restrict__ gts, const float* __restrict__ preds,
                  const _Float16* __restrict__ Qg, const _Float16* __restrict__ Cg,
                  const _Float16* __restrict__ Qp, const _Float16* __restrict__ Cp,
                  double* __restrict__ acc) {
  __shared__ float T[4][32][KSEL + 1];   // +1 pad: stride 17 -> conflict-free
  __shared__ float TB[CW][32];

  const int t    = threadIdx.x;
  const int lane = t & 63;
  const int w    = t >> 6;
  const int col  = lane & 31;
  const int half = lane >> 5;
  const int b    = blockIdx.y;
  const int strip= blockIdx.x;

  const size_t qoff = ((size_t)(b * NPTS + strip * 32 + col)) * 16 + half * 8;
  const f16x8 qg = *(const f16x8*)(Qg + qoff);
  const f16x8 qp = *(const f16x8*)(Qp + qoff);
  f32x16 zz;
#pragma unroll
  for (int i = 0; i < 16; ++i) zz[i] = 0.f;

#define TREE16(f)                                                        \
  do {                                                                   \
    __syncthreads();                                                     \
    if (w >= 4 && half == 0) {                                           \
      _Pragma("unroll") for (int i = 0; i < KSEL; ++i) T[w-4][col][i] = (f)[i]; \
    }                                                                    \
    __syncthreads();                                                     \
    if (w < 4) { float g[KSEL];                                          \
      _Pragma("unroll") for (int i = 0; i < KSEL; ++i) g[i] = T[w][col][i]; \
      keep16((f), g); }                                                  \
    __syncthreads();                                                     \
    if ((w == 2 || w == 3) && half == 0) {                               \
      _Pragma("unroll") for (int i = 0; i < KSEL; ++i) T[w-2][col][i] = (f)[i]; \
    }                                                                    \
    __syncthreads();                                                     \
    if (w < 2) { float g[KSEL];                                          \
      _Pragma("unroll") for (int i = 0; i < KSEL; ++i) g[i] = T[w][col][i]; \
      keep16((f), g); }                                                  \
    __syncthreads();                                                     \
    if (w == 1 && half == 0) {                                           \
      _Pragma("unroll") for (int i = 0; i < KSEL; ++i) T[0][col][i] = (f)[i]; \
    }                                                                    \
    __syncthreads();                                                     \
    if (w == 0) { float g[KSEL];                                         \
      _Pragma("unroll") for (int i = 0; i < KSEL; ++i) g[i] = T[0][col][i]; \
      keep16((f), g); }                                                  \
  } while (0)

  // ---- Loop 2: cands = gts.  B-search (queries gts) + C-min (queries preds) ----
  float h2l[16];
#pragma unroll
  for (int i = 0; i < 16; ++i) h2l[i] = 1e30f;
  float bw = 1e30f;
  {
    const _Float16* cb = Cg + ((size_t)(b * NPTS + w * 512)) * 16;
#pragma unroll 2
    for (int tile = 0; tile < TPW; ++tile) {
      const f16x8 at = *(const f16x8*)(cb + (size_t)(tile * 32 + col) * 16 + half * 8);
      const f32x16 aB = __builtin_amdgcn_mfma_f32_32x32x16_f16(at, qg, zz, 0, 0, 0);
      const f32x16 aC = __builtin_amdgcn_mfma_f32_32x32x16_f16(at, qp, zz, 0, 0, 0);
#pragma unroll
      for (int r = 0; r < 16; ++r) insert2(h2l + (r >> 1) * 2, aB[r]);
      const float c0 = min3f(aC[0],  aC[1],  aC[2]);
      const float c1 = min3f(aC[3],  aC[4],  aC[5]);
      const float c2 = min3f(aC[6],  aC[7],  aC[8]);
      const float c3 = min3f(aC[9],  aC[10], aC[11]);
      const float c4 = min3f(aC[12], aC[13], aC[14]);
      const float d0 = min3f(c0, c1, aC[15]);
      const float d1 = min3f(c2, c3, c4);
      bw = min3f(bw, d0, d1);
    }
  }
  float f2[KSEL];
  {
    sort8x2(f2, h2l);
    float g[KSEL];
#pragma unroll
    for (int i = 0; i < KSEL; ++i) g[i] = __shfl_xor(f2[i], 32);
    keep16(f2, g);
    bw = fminf(bw, __shfl_xor(bw, 32));
  }
  if (half == 0) TB[w][col] = bw;
  TREE16(f2);            // f2 final in wave 0
  __syncthreads();
  if (w == 0) {
#pragma unroll
    for (int ww = 1; ww < CW; ++ww) bw = fminf(bw, TB[ww][col]);
  }

  // ---- Loop 1: cands = preds, queries = gts (A-search) ----
  float h1l[16];
#pragma unroll
  for (int i = 0; i < 16; ++i) h1l[i] = 1e30f;
  {
    const _Float16* cb = Cp + ((size_t)(b * NPTS + w * 512)) * 16;
#pragma unroll 2
    for (int tile = 0; tile < TPW; ++tile) {
      const f16x8 at = *(const f16x8*)(cb + (size_t)(tile * 32 + col) * 16 + half * 8);
      const f32x16 aA = __builtin_amdgcn_mfma_f32_32x32x16_f16(at, qg, zz, 0, 0, 0);
#pragma unroll
      for (int r = 0; r < 16; ++r) insert2(h1l + (r >> 1) * 2, aA[r]);
    }
  }
  float f1[KSEL];
  {
    sort8x2(f1, h1l);
    float g[KSEL];
#pragma unroll
    for (int i = 0; i < KSEL; ++i) g[i] = __shfl_xor(f1[i], 32);
    keep16(f1, g);
  }
  TREE16(f1);            // f1 final in wave 0

  // ---- epilogue (wave 0): re-add query norms, accumulate ----
  if (w == 0) {
    const float* gq = gts   + ((size_t)(b * NPTS) + strip * 32 + col) * 3;
    const float qn = fmaf(gq[0], gq[0], fmaf(gq[1], gq[1], gq[2] * gq[2]));
    const float* pq = preds + ((size_t)(b * NPTS) + strip * 32 + col) * 3;
    const float pn = fmaf(pq[0], pq[0], fmaf(pq[1], pq[1], pq[2] * pq[2]));

    float v1 = bw + pn;         // loss_1 term (pred query)
    float v2 = f1[0] + qn;      // loss_2 term (gt query)
    float v3 = 0.0f;            // density (qn cancels exactly)
#pragma unroll
    for (int i = 0; i < KSEL; ++i) {
      const float df = f1[i] - f2[i];
      v3 = fmaf(df, df, v3);
    }
    if (half) { v1 = 0.f; v2 = 0.f; v3 = 0.f; }   // halves are duplicates
#pragma unroll
    for (int off = 32; off >= 1; off >>= 1) {
      v1 += __shfl_xor(v1, off);
      v2 += __shfl_xor(v2, off);
      v3 += __shfl_xor(v3, off);
    }
    if (lane == 0) {
      const int slot = (strip + 13 * b) & (NSLOTS - 1);
      atomicAdd(&acc[0 * NSLOTS + slot], (double)v1);
      atomicAdd(&acc[1 * NSLOTS + slot], (double)v2);
      atomicAdd(&acc[2 * NSLOTS + slot], (double)v3);
    }
  }
#undef TREE16
}

extern "C" __global__ void finalize_kernel(const double* __restrict__ acc,
                                           float* __restrict__ out) {
  const int l = threadIdx.x;  // 64 threads
  double a = acc[l], b = acc[NSLOTS + l], c = acc[2 * NSLOTS + l];
#pragma unroll
  for (int off = 32; off >= 1; off >>= 1) {
    a += __shfl_xor(a, off);
    b += __shfl_xor(b, off);
    c += __shfl_xor(c, off);
  }
  if (l == 0) {
    const double loss1 = a / (double)((size_t)NB * NPTS);
    const double loss2 = b / (double)((size_t)NB * NPTS);
    const double dens  = c / (double)((size_t)NB * NPTS * KSEL);
    out[0] = (float)(loss1 + loss2);
    out[1] = (float)dens;
  }
}

extern "C" void kernel_launch(void* const* d_in, const int* in_sizes, int n_in,
                              void* d_out, int out_size, void* d_ws, size_t ws_size,
                              hipStream_t stream) {
  const float* gts   = (const float*)d_in[0];
  const float* preds = (const float*)d_in[1];
  char* ws = (char*)d_ws;
  const size_t ARR = (size_t)HALFPTS * 16 * sizeof(_Float16);   // 1 MiB each
  _Float16* Qg = (_Float16*)(ws + 0 * ARR);
  _Float16* Cg = (_Float16*)(ws + 1 * ARR);
  _Float16* Qp = (_Float16*)(ws + 2 * ARR);
  _Float16* Cp = (_Float16*)(ws + 3 * ARR);
  double*  acc = (double*)(ws + 4 * ARR);
  float*   out = (float*)d_out;

  hipLaunchKernelGGL(prep_kernel, dim3(2 * HALFPTS / 256), dim3(256), 0, stream,
                     gts, preds, Qg, Cg, Qp, Cp);
  hipLaunchKernelGGL(init_acc, dim3(1), dim3(256), 0, stream, acc);
  hipLaunchKernelGGL(fused_kernel, dim3(NPTS / 32, NB), dim3(THREADS), 0, stream,
                     gts, preds, Qg, Cg, Qp, Cp, acc);
  hipLaunchKernelGGL(finalize_kernel, dim3(1), dim3(64), 0, stream, acc, out);
}

// Round 10
// 36.383 us; speedup vs baseline: 2.4629x; 1.6362x over previous
//
#include <hip/hip_runtime.h>
#include <hip/hip_bf16.h>
#include <hip/hip_fp16.h>

#define NB      8
#define NPTS    4096
#define KSEL    16
#define THREADS 256
#define CW      4            // candidate-split waves per block
#define TPW     32           // tiles per wave per search = NPTS/(CW*32)
#define NSLOTS  64
#define HALFPTS (NB*NPTS)    // 32768 points per array

typedef _Float16 f16x8 __attribute__((ext_vector_type(8)));
typedef float    f32x16 __attribute__((ext_vector_type(16)));

__device__ __forceinline__ void ce(float& a, float& b) {
  const float lo = fminf(a, b), hi = fmaxf(a, b);
  a = lo; b = hi;
}
__device__ __forceinline__ float min3f(float a, float b, float c) {
  return fminf(fminf(a, b), c);              // fuses to v_min3_f32
}

// two sorted-2 -> sorted-4 (4 ce)
__device__ __forceinline__ void m22(float* o, const float* a, const float* b) {
  o[0]=a[0]; o[1]=a[1]; o[2]=b[1]; o[3]=b[0];
  ce(o[0],o[2]); ce(o[1],o[3]);
  ce(o[0],o[1]); ce(o[2],o[3]);
}
// two sorted-4 -> sorted-8 (12 ce)
__device__ __forceinline__ void m44(float* o, const float* a, const float* b) {
  o[0]=a[0]; o[1]=a[1]; o[2]=a[2]; o[3]=a[3];
  o[4]=b[3]; o[5]=b[2]; o[6]=b[1]; o[7]=b[0];
  ce(o[0],o[4]); ce(o[1],o[5]); ce(o[2],o[6]); ce(o[3],o[7]);
  ce(o[0],o[2]); ce(o[1],o[3]); ce(o[4],o[6]); ce(o[5],o[7]);
  ce(o[0],o[1]); ce(o[2],o[3]); ce(o[4],o[5]); ce(o[6],o[7]);
}
// two sorted-8 -> sorted-16 (32 ce)
__device__ __forceinline__ void m88(float* o, const float* a, const float* b) {
#pragma unroll
  for (int i = 0; i < 8; ++i) { o[i] = a[i]; o[15 - i] = b[i]; }
#pragma unroll
  for (int d = 8; d >= 1; d >>= 1)
#pragma unroll
    for (int i = 0; i < 16; ++i)
      if ((i & d) == 0) ce(o[i], o[i + d]);
}
// full merge-sort of 16 unsorted values: f = sorted(h); h clobbered.
__device__ __forceinline__ void sort16(float* f, float* h) {
#pragma unroll
  for (int i = 0; i < 16; i += 2) ce(h[i], h[i + 1]);
  float s[16];
  m22(s + 0, h + 0, h + 2);  m22(s + 4,  h + 4,  h + 6);
  m22(s + 8, h + 8, h + 10); m22(s + 12, h + 12, h + 14);
  m44(h + 0, s + 0, s + 4);  m44(h + 8, s + 8, s + 12);
  m88(f, h + 0, h + 8);
}
// keep smallest-16 of two sorted-16 lists, in place in h.
__device__ __forceinline__ void keep16(float* h, const float* g) {
#pragma unroll
  for (int i = 0; i < KSEL; ++i) h[i] = fminf(h[i], g[KSEL - 1 - i]);
#pragma unroll
  for (int d = 8; d >= 1; d >>= 1)
#pragma unroll
    for (int i = 0; i < KSEL; ++i)
      if ((i & d) == 0) ce(h[i], h[i + d]);
}

// Per point: Q-role K-vector [xh,xh,xl, yh,yh,yl, zh,zh,zl, 1,1, 0...] and
// C-role [(-2x)h,(-2x)l,(-2x)h, ..., cnh,cnl, 0...]; dot(Q,C) = -2 q.c + |c|^2
// with ~1e-6 abs error (3-term hi/lo products, f32 MFMA accumulation).
extern "C" __global__ __launch_bounds__(256)
void prep_kernel(const float* __restrict__ gts, const float* __restrict__ preds,
                 _Float16* __restrict__ Qg, _Float16* __restrict__ Cg,
                 _Float16* __restrict__ Qp, _Float16* __restrict__ Cp) {
  const int i = blockIdx.x * 256 + threadIdx.x;     // 0..2*HALFPTS-1
  const bool isg = i < HALFPTS;
  const float* __restrict__ src = isg ? gts : preds;
  const int j = isg ? i : i - HALFPTS;
  const float x = src[3*j], y = src[3*j+1], z = src[3*j+2];
  const float cn = fmaf(x, x, fmaf(y, y, z * z));

  const _Float16 xh = (_Float16)x, yh = (_Float16)y, zh = (_Float16)z;
  const _Float16 xl = (_Float16)(x - (float)xh);
  const _Float16 yl = (_Float16)(y - (float)yh);
  const _Float16 zl = (_Float16)(z - (float)zh);
  const float mx = -2.f*x, my = -2.f*y, mz = -2.f*z;
  const _Float16 mxh = (_Float16)mx, myh = (_Float16)my, mzh = (_Float16)mz;
  const _Float16 mxl = (_Float16)(mx - (float)mxh);
  const _Float16 myl = (_Float16)(my - (float)myh);
  const _Float16 mzl = (_Float16)(mz - (float)mzh);
  const _Float16 cnh = (_Float16)cn;
  const _Float16 cnl = (_Float16)(cn - (float)cnh);
  const _Float16 one = (_Float16)1.0f, zr = (_Float16)0.0f;

  _Float16* Q = (isg ? Qg : Qp) + (size_t)j * 16;
  _Float16* C = (isg ? Cg : Cp) + (size_t)j * 16;
  Q[0]=xh; Q[1]=xh; Q[2]=xl; Q[3]=yh; Q[4]=yh; Q[5]=yl;
  Q[6]=zh; Q[7]=zh; Q[8]=zl; Q[9]=one; Q[10]=one;
  Q[11]=zr; Q[12]=zr; Q[13]=zr; Q[14]=zr; Q[15]=zr;
  C[0]=mxh; C[1]=mxl; C[2]=mxh; C[3]=myh; C[4]=myl; C[5]=myh;
  C[6]=mzh; C[7]=mzl; C[8]=mzh; C[9]=cnh; C[10]=cnl;
  C[11]=zr; C[12]=zr; C[13]=zr; C[14]=zr; C[15]=zr;
}

extern "C" __global__ void init_acc(double* acc) {
  const int t = threadIdx.x;
  if (t < 3 * NSLOTS) acc[t] = 0.0;
}

// Block: 4 waves, one 32-query strip; wave w owns cand range [w*1024, w*1024+1024)
// = 32 tiles. Per tile: 3 MFMAs (A: pred-cands/gt-queries; B: gt-cands/gt-queries;
// C: gt-cands/pred-queries). Selection: top-1 x 16 row-lists (1 fmin/score) for
// A and B; min3-tree for C. Merge: sort16 + shfl(32) + single 2-level LDS tree.
extern "C" __global__ __launch_bounds__(THREADS, 4)
void fused_kernel(const float* __restrict__ gts, const float* __restrict__ preds,
                  const _Float16* __restrict__ Qg, const _Float16* __restrict__ Cg,
                  const _Float16* __restrict__ Qp, const _Float16* __restrict__ Cp,
                  double* __restrict__ acc) {
  __shared__ float T1[2][32][KSEL + 1];   // +1 pad: conflict-free
  __shared__ float T2[2][32][KSEL + 1];
  __shared__ float TB[CW][32];

  const int t    = threadIdx.x;
  const int lane = t & 63;
  const int w    = t >> 6;
  const int col  = lane & 31;
  const int half = lane >> 5;
  const int b    = blockIdx.y;
  const int strip= blockIdx.x;

  const size_t qoff = ((size_t)(b * NPTS + strip * 32 + col)) * 16 + half * 8;
  const f16x8 qg = *(const f16x8*)(Qg + qoff);
  const f16x8 qp = *(const f16x8*)(Qp + qoff);
  f32x16 zz;
#pragma unroll
  for (int i = 0; i < 16; ++i) zz[i] = 0.f;

  float hA[16], hB[16];
#pragma unroll
  for (int i = 0; i < 16; ++i) { hA[i] = 1e30f; hB[i] = 1e30f; }
  float bw = 1e30f;

  const _Float16* __restrict__ cbg = Cg + ((size_t)(b * NPTS + w * 1024)) * 16;
  const _Float16* __restrict__ cbp = Cp + ((size_t)(b * NPTS + w * 1024)) * 16;

#pragma unroll 2
  for (int tile = 0; tile < TPW; ++tile) {
    const size_t off = (size_t)(tile * 32 + col) * 16 + half * 8;
    const f16x8 ag = *(const f16x8*)(cbg + off);
    const f16x8 ap = *(const f16x8*)(cbp + off);
    const f32x16 aB = __builtin_amdgcn_mfma_f32_32x32x16_f16(ag, qg, zz, 0, 0, 0);
    const f32x16 aC = __builtin_amdgcn_mfma_f32_32x32x16_f16(ag, qp, zz, 0, 0, 0);
    const f32x16 aA = __builtin_amdgcn_mfma_f32_32x32x16_f16(ap, qg, zz, 0, 0, 0);
#pragma unroll
    for (int r = 0; r < 16; ++r) {
      hB[r] = fminf(hB[r], aB[r]);    // top-1 per row-slice (dist2 top-k)
      hA[r] = fminf(hA[r], aA[r]);    // top-1 per row-slice (dist1 top-k)
    }
    const float c0 = min3f(aC[0],  aC[1],  aC[2]);
    const float c1 = min3f(aC[3],  aC[4],  aC[5]);
    const float c2 = min3f(aC[6],  aC[7],  aC[8]);
    const float c3 = min3f(aC[9],  aC[10], aC[11]);
    const float c4 = min3f(aC[12], aC[13], aC[14]);
    const float d0 = min3f(c0, c1, aC[15]);
    const float d1 = min3f(c2, c3, c4);
    bw = min3f(bw, d0, d1);           // loss_1 partial (pred query col)
  }

  // ---- per-wave: sort the 16 slice-minima, merge halves ----
  float f1[KSEL], f2[KSEL];
  sort16(f1, hA);
  sort16(f2, hB);
  {
    float g[KSEL];
#pragma unroll
    for (int i = 0; i < KSEL; ++i) g[i] = __shfl_xor(f1[i], 32);
    keep16(f1, g);
#pragma unroll
    for (int i = 0; i < KSEL; ++i) g[i] = __shfl_xor(f2[i], 32);
    keep16(f2, g);
  }
  bw = fminf(bw, __shfl_xor(bw, 32));
  if (half == 0) TB[w][col] = bw;

  // ---- single 2-level LDS tree for both lists: 4 -> 2 -> 1 ----
  __syncthreads();
  if (w >= 2 && half == 0) {
#pragma unroll
    for (int i = 0; i < KSEL; ++i) { T1[w-2][col][i] = f1[i]; T2[w-2][col][i] = f2[i]; }
  }
  __syncthreads();
  if (w < 2) {
    float g[KSEL];
#pragma unroll
    for (int i = 0; i < KSEL; ++i) g[i] = T1[w][col][i];
    keep16(f1, g);
#pragma unroll
    for (int i = 0; i < KSEL; ++i) g[i] = T2[w][col][i];
    keep16(f2, g);
  }
  __syncthreads();
  if (w == 1 && half == 0) {
#pragma unroll
    for (int i = 0; i < KSEL; ++i) { T1[0][col][i] = f1[i]; T2[0][col][i] = f2[i]; }
  }
  __syncthreads();
  if (w == 0) {
    float g[KSEL];
#pragma unroll
    for (int i = 0; i < KSEL; ++i) g[i] = T1[0][col][i];
    keep16(f1, g);
#pragma unroll
    for (int i = 0; i < KSEL; ++i) g[i] = T2[0][col][i];
    keep16(f2, g);
#pragma unroll
    for (int ww = 1; ww < CW; ++ww) bw = fminf(bw, TB[ww][col]);

    // ---- epilogue: re-add query norms, accumulate ----
    const float* gq = gts   + ((size_t)(b * NPTS) + strip * 32 + col) * 3;
    const float qn = fmaf(gq[0], gq[0], fmaf(gq[1], gq[1], gq[2] * gq[2]));
    const float* pq = preds + ((size_t)(b * NPTS) + strip * 32 + col) * 3;
    const float pn = fmaf(pq[0], pq[0], fmaf(pq[1], pq[1], pq[2] * pq[2]));

    float v1 = bw + pn;         // loss_1 term (pred query)
    float v2 = f1[0] + qn;      // loss_2 term (gt query)
    float v3 = 0.0f;            // density (qn cancels exactly)
#pragma unroll
    for (int i = 0; i < KSEL; ++i) {
      const float df = f1[i] - f2[i];
      v3 = fmaf(df, df, v3);
    }
    if (half) { v1 = 0.f; v2 = 0.f; v3 = 0.f; }   // halves hold duplicates
#pragma unroll
    for (int off = 32; off >= 1; off >>= 1) {
      v1 += __shfl_xor(v1, off);
      v2 += __shfl_xor(v2, off);
      v3 += __shfl_xor(v3, off);
    }
    if (lane == 0) {
      const int slot = (strip + 13 * b) & (NSLOTS - 1);
      atomicAdd(&acc[0 * NSLOTS + slot], (double)v1);
      atomicAdd(&acc[1 * NSLOTS + slot], (double)v2);
      atomicAdd(&acc[2 * NSLOTS + slot], (double)v3);
    }
  }
}

extern "C" __global__ void finalize_kernel(const double* __restrict__ acc,
                                           float* __restrict__ out) {
  const int l = threadIdx.x;  // 64 threads
  double a = acc[l], b = acc[NSLOTS + l], c = acc[2 * NSLOTS + l];
#pragma unroll
  for (int off = 32; off >= 1; off >>= 1) {
    a += __shfl_xor(a, off);
    b += __shfl_xor(b, off);
    c += __shfl_xor(c, off);
  }
  if (l == 0) {
    const double loss1 = a / (double)((size_t)NB * NPTS);
    const double loss2 = b / (double)((size_t)NB * NPTS);
    const double dens  = c / (double)((size_t)NB * NPTS * KSEL);
    out[0] = (float)(loss1 + loss2);
    out[1] = (float)dens;
  }
}

extern "C" void kernel_launch(void* const* d_in, const int* in_sizes, int n_in,
                              void* d_out, int out_size, void* d_ws, size_t ws_size,
                              hipStream_t stream) {
  const float* gts   = (const float*)d_in[0];
  const float* preds = (const float*)d_in[1];
  char* ws = (char*)d_ws;
  const size_t ARR = (size_t)HALFPTS * 16 * sizeof(_Float16);   // 1 MiB each
  _Float16* Qg = (_Float16*)(ws + 0 * ARR);
  _Float16* Cg = (_Float16*)(ws + 1 * ARR);
  _Float16* Qp = (_Float16*)(ws + 2 * ARR);
  _Float16* Cp = (_Float16*)(ws + 3 * ARR);
  double*  acc = (double*)(ws + 4 * ARR);
  float*   out = (float*)d_out;

  hipLaunchKernelGGL(prep_kernel, dim3(2 * HALFPTS / 256), dim3(256), 0, stream,
                     gts, preds, Qg, Cg, Qp, Cp);
  hipLaunchKernelGGL(init_acc, dim3(1), dim3(256), 0, stream, acc);
  hipLaunchKernelGGL(fused_kernel, dim3(NPTS / 32, NB), dim3(THREADS), 0, stream,
                     gts, preds, Qg, Cg, Qp, Cp, acc);
  hipLaunchKernelGGL(finalize_kernel, dim3(1), dim3(64), 0, stream, acc, out);
}

// Round 11
// 34.748 us; speedup vs baseline: 2.5787x; 1.0471x over previous
//
#include <hip/hip_runtime.h>
#include <hip/hip_bf16.h>
#include <hip/hip_fp16.h>

#define NB      8
#define NPTS    4096
#define KSEL    16
#define THREADS 768         // 12 waves: 4xB, 4xC, 4xA
#define NSLOTS  64
#define HALFPTS (NB*NPTS)   // 32768 points per array

typedef _Float16 f16x8 __attribute__((ext_vector_type(8)));
typedef float    f32x16 __attribute__((ext_vector_type(16)));

__device__ __forceinline__ void ce(float& a, float& b) {
  const float lo = fminf(a, b), hi = fmaxf(a, b);
  a = lo; b = hi;
}
__device__ __forceinline__ float min3f(float a, float b, float c) {
  return fminf(fminf(a, b), c);              // fuses to v_min3_f32
}

// two sorted-2 -> sorted-4 (4 ce)
__device__ __forceinline__ void m22(float* o, const float* a, const float* b) {
  o[0]=a[0]; o[1]=a[1]; o[2]=b[1]; o[3]=b[0];
  ce(o[0],o[2]); ce(o[1],o[3]);
  ce(o[0],o[1]); ce(o[2],o[3]);
}
// two sorted-4 -> sorted-8 (12 ce)
__device__ __forceinline__ void m44(float* o, const float* a, const float* b) {
  o[0]=a[0]; o[1]=a[1]; o[2]=a[2]; o[3]=a[3];
  o[4]=b[3]; o[5]=b[2]; o[6]=b[1]; o[7]=b[0];
  ce(o[0],o[4]); ce(o[1],o[5]); ce(o[2],o[6]); ce(o[3],o[7]);
  ce(o[0],o[2]); ce(o[1],o[3]); ce(o[4],o[6]); ce(o[5],o[7]);
  ce(o[0],o[1]); ce(o[2],o[3]); ce(o[4],o[5]); ce(o[6],o[7]);
}
// two sorted-8 -> sorted-16 (32 ce)
__device__ __forceinline__ void m88(float* o, const float* a, const float* b) {
#pragma unroll
  for (int i = 0; i < 8; ++i) { o[i] = a[i]; o[15 - i] = b[i]; }
#pragma unroll
  for (int d = 8; d >= 1; d >>= 1)
#pragma unroll
    for (int i = 0; i < 16; ++i)
      if ((i & d) == 0) ce(o[i], o[i + d]);
}
// keep smallest-16 of two sorted-16 lists, in place in h.
__device__ __forceinline__ void keep16(float* h, const float* g) {
#pragma unroll
  for (int i = 0; i < KSEL; ++i) h[i] = fminf(h[i], g[KSEL - 1 - i]);
#pragma unroll
  for (int d = 8; d >= 1; d >>= 1)
#pragma unroll
    for (int i = 0; i < KSEL; ++i)
      if ((i & d) == 0) ce(h[i], h[i + d]);
}

// Per point: Q-role K-vector [xh,xh,xl, yh,yh,yl, zh,zh,zl, 1,1, 0...] and
// C-role [(-2x)h,(-2x)l,(-2x)h, ..., cnh,cnl, 0...]; dot(Q,C) = -2 q.c + |c|^2
// with ~1e-6 abs error (3-term hi/lo products, f32 MFMA accumulation).
// Also zeroes the accumulator slots (block 0) — init_acc folded in.
extern "C" __global__ __launch_bounds__(256)
void prep_kernel(const float* __restrict__ gts, const float* __restrict__ preds,
                 _Float16* __restrict__ Qg, _Float16* __restrict__ Cg,
                 _Float16* __restrict__ Qp, _Float16* __restrict__ Cp,
                 double* __restrict__ acc) {
  if (blockIdx.x == 0 && threadIdx.x < 3 * NSLOTS) acc[threadIdx.x] = 0.0;
  const int i = blockIdx.x * 256 + threadIdx.x;     // 0..2*HALFPTS-1
  const bool isg = i < HALFPTS;
  const float* __restrict__ src = isg ? gts : preds;
  const int j = isg ? i : i - HALFPTS;
  const float x = src[3*j], y = src[3*j+1], z = src[3*j+2];
  const float cn = fmaf(x, x, fmaf(y, y, z * z));

  const _Float16 xh = (_Float16)x, yh = (_Float16)y, zh = (_Float16)z;
  const _Float16 xl = (_Float16)(x - (float)xh);
  const _Float16 yl = (_Float16)(y - (float)yh);
  const _Float16 zl = (_Float16)(z - (float)zh);
  const float mx = -2.f*x, my = -2.f*y, mz = -2.f*z;
  const _Float16 mxh = (_Float16)mx, myh = (_Float16)my, mzh = (_Float16)mz;
  const _Float16 mxl = (_Float16)(mx - (float)mxh);
  const _Float16 myl = (_Float16)(my - (float)myh);
  const _Float16 mzl = (_Float16)(mz - (float)mzh);
  const _Float16 cnh = (_Float16)cn;
  const _Float16 cnl = (_Float16)(cn - (float)cnh);
  const _Float16 one = (_Float16)1.0f, zr = (_Float16)0.0f;

  _Float16* Q = (isg ? Qg : Qp) + (size_t)j * 16;
  _Float16* C = (isg ? Cg : Cp) + (size_t)j * 16;
  Q[0]=xh; Q[1]=xh; Q[2]=xl; Q[3]=yh; Q[4]=yh; Q[5]=yl;
  Q[6]=zh; Q[7]=zh; Q[8]=zl; Q[9]=one; Q[10]=one;
  Q[11]=zr; Q[12]=zr; Q[13]=zr; Q[14]=zr; Q[15]=zr;
  C[0]=mxh; C[1]=mxl; C[2]=mxh; C[3]=myh; C[4]=myl; C[5]=myh;
  C[6]=mzh; C[7]=mzl; C[8]=mzh; C[9]=cnh; C[10]=cnl;
  C[11]=zr; C[12]=zr; C[13]=zr; C[14]=zr; C[15]=zr;
}

// Block: 12 waves on one 32-query strip. Even waves 0,2,4,6: B-search (gt-cand x
// gt-q, top-k); odd waves 1,3,5,7: C-search (gt-cand x pred-q, min) on the SAME
// cand range as their B partner (L1 reuse); waves 8-11: A-search (pred-cand x
// gt-q, top-k). Each wave: 1024 cands = 32 MFMA tiles, ONE acc stream (fits
// 64-reg quantum -> 8 waves/SIMD). Selection: h[8] row-pair slices via v_min3.
extern "C" __global__ __launch_bounds__(THREADS, 8)
void fused_kernel(const float* __restrict__ gts, const float* __restrict__ preds,
                  const _Float16* __restrict__ Qg, const _Float16* __restrict__ Cg,
                  const _Float16* __restrict__ Qp, const _Float16* __restrict__ Cp,
                  double* __restrict__ acc) {
  __shared__ float TQ[2][2][32][KSEL + 1];   // [search B=0/A=1][slot][col][pad17]
  __shared__ float TCm[4][32];

  const int t    = threadIdx.x;
  const int lane = t & 63;
  const int w    = t >> 6;          // 0..11
  const int col  = lane & 31;
  const int half = lane >> 5;
  const int b    = blockIdx.y;
  const int strip= blockIdx.x;

  const bool isC = (w < 8) && (w & 1);
  const bool isA = (w >= 8);
  const int  S   = isA ? 1 : 0;
  const int  sub = isA ? (w - 8) : (w >> 1);

  const size_t qoff = ((size_t)(b * NPTS + strip * 32 + col)) * 16 + half * 8;
  const f16x8 q = isC ? *(const f16x8*)(Qp + qoff) : *(const f16x8*)(Qg + qoff);

  const _Float16* __restrict__ cb = (isA ? Cp : Cg) + ((size_t)(b * NPTS + sub * 1024)) * 16;
  const _Float16* __restrict__ p  = cb + (size_t)col * 16 + half * 8;

  f32x16 zz;
#pragma unroll
  for (int i = 0; i < 16; ++i) zz[i] = 0.f;

  float f[KSEL];
  float bw = 1e30f;

  if (!isC) {
    float h[8];
#pragma unroll
    for (int i = 0; i < 8; ++i) h[i] = 1e30f;
    for (int tile = 0; tile < 32; ++tile) {
      const f16x8 at = *(const f16x8*)(p + (size_t)tile * 512);
      const f32x16 a = __builtin_amdgcn_mfma_f32_32x32x16_f16(at, q, zz, 0, 0, 0);
#pragma unroll
      for (int j = 0; j < 8; ++j)
        h[j] = min3f(h[j], a[2*j], a[2*j + 1]);   // top-1 per row-pair slice
    }
    // sort8 -> f8; cross-half merge -> sorted-16 per lane
    ce(h[0],h[1]); ce(h[2],h[3]); ce(h[4],h[5]); ce(h[6],h[7]);
    float s4a[4], s4b[4], f8[8], g8[8];
    m22(s4a, h + 0, h + 2); m22(s4b, h + 4, h + 6);
    m44(f8, s4a, s4b);
#pragma unroll
    for (int i = 0; i < 8; ++i) g8[i] = __shfl_xor(f8[i], 32);
    m88(f, f8, g8);
  } else {
    for (int tile = 0; tile < 32; ++tile) {
      const f16x8 at = *(const f16x8*)(p + (size_t)tile * 512);
      const f32x16 a = __builtin_amdgcn_mfma_f32_32x32x16_f16(at, q, zz, 0, 0, 0);
      const float c0 = min3f(a[0],  a[1],  a[2]);
      const float c1 = min3f(a[3],  a[4],  a[5]);
      const float c2 = min3f(a[6],  a[7],  a[8]);
      const float c3 = min3f(a[9],  a[10], a[11]);
      const float c4 = min3f(a[12], a[13], a[14]);
      const float d0 = min3f(c0, c1, a[15]);
      const float d1 = min3f(c2, c3, c4);
      bw = min3f(bw, d0, d1);
    }
    bw = fminf(bw, __shfl_xor(bw, 32));
  }

  // ---- cross-wave merge: per search 4 -> 2 -> 1; C: 4-way min ---------------
  const bool topk = !isC;
  if (topk && sub >= 2 && half == 0) {
#pragma unroll
    for (int i = 0; i < KSEL; ++i) TQ[S][sub - 2][col][i] = f[i];
  }
  if (isC && half == 0) TCm[sub][col] = bw;
  __syncthreads();
  if (topk && sub < 2) {
    float g[KSEL];
#pragma unroll
    for (int i = 0; i < KSEL; ++i) g[i] = TQ[S][sub][col][i];
    keep16(f, g);
  }
  if (w == 1)
    bw = fminf(fminf(TCm[0][col], TCm[1][col]), fminf(TCm[2][col], TCm[3][col]));
  __syncthreads();
  if (topk && sub == 1 && half == 0) {
#pragma unroll
    for (int i = 0; i < KSEL; ++i) TQ[S][0][col][i] = f[i];
  }
  __syncthreads();
  if (topk && sub == 0) {
    float g[KSEL];
#pragma unroll
    for (int i = 0; i < KSEL; ++i) g[i] = TQ[S][0][col][i];
    keep16(f, g);                  // finals: B in w0, A in w8
  }
  if (w == 8 && half == 0) {
#pragma unroll
    for (int i = 0; i < KSEL; ++i) TQ[1][1][col][i] = f[i];   // export A-final
  }
  if (w == 1 && half == 0) TCm[0][col] = bw;                  // export C-final
  __syncthreads();

  if (w == 0) {   // has B-final in f; read A-final (f1) and C-final (bw)
    float f1[KSEL];
#pragma unroll
    for (int i = 0; i < KSEL; ++i) f1[i] = TQ[1][1][col][i];
    const float bwf = TCm[0][col];

    const float* gq = gts   + ((size_t)(b * NPTS) + strip * 32 + col) * 3;
    const float qn = fmaf(gq[0], gq[0], fmaf(gq[1], gq[1], gq[2] * gq[2]));
    const float* pq = preds + ((size_t)(b * NPTS) + strip * 32 + col) * 3;
    const float pn = fmaf(pq[0], pq[0], fmaf(pq[1], pq[1], pq[2] * pq[2]));

    float v1 = bwf + pn;          // loss_1 term (pred query)
    float v2 = f1[0] + qn;        // loss_2 term (gt query; A = dist1 top-k)
    float v3 = 0.0f;              // density: (val_1 - val_2)^2, qn cancels
#pragma unroll
    for (int i = 0; i < KSEL; ++i) {
      const float df = f1[i] - f[i];
      v3 = fmaf(df, df, v3);
    }
    if (half) { v1 = 0.f; v2 = 0.f; v3 = 0.f; }   // halves hold duplicates
#pragma unroll
    for (int off = 32; off >= 1; off >>= 1) {
      v1 += __shfl_xor(v1, off);
      v2 += __shfl_xor(v2, off);
      v3 += __shfl_xor(v3, off);
    }
    if (lane == 0) {
      const int slot = (strip + 13 * b) & (NSLOTS - 1);
      atomicAdd(&acc[0 * NSLOTS + slot], (double)v1);
      atomicAdd(&acc[1 * NSLOTS + slot], (double)v2);
      atomicAdd(&acc[2 * NSLOTS + slot], (double)v3);
    }
  }
}

extern "C" __global__ void finalize_kernel(const double* __restrict__ acc,
                                           float* __restrict__ out) {
  const int l = threadIdx.x;  // 64 threads
  double a = acc[l], b = acc[NSLOTS + l], c = acc[2 * NSLOTS + l];
#pragma unroll
  for (int off = 32; off >= 1; off >>= 1) {
    a += __shfl_xor(a, off);
    b += __shfl_xor(b, off);
    c += __shfl_xor(c, off);
  }
  if (l == 0) {
    const double loss1 = a / (double)((size_t)NB * NPTS);
    const double loss2 = b / (double)((size_t)NB * NPTS);
    const double dens  = c / (double)((size_t)NB * NPTS * KSEL);
    out[0] = (float)(loss1 + loss2);
    out[1] = (float)dens;
  }
}

extern "C" void kernel_launch(void* const* d_in, const int* in_sizes, int n_in,
                              void* d_out, int out_size, void* d_ws, size_t ws_size,
                              hipStream_t stream) {
  const float* gts   = (const float*)d_in[0];
  const float* preds = (const float*)d_in[1];
  char* ws = (char*)d_ws;
  const size_t ARR = (size_t)HALFPTS * 16 * sizeof(_Float16);   // 1 MiB each
  _Float16* Qg = (_Float16*)(ws + 0 * ARR);
  _Float16* Cg = (_Float16*)(ws + 1 * ARR);
  _Float16* Qp = (_Float16*)(ws + 2 * ARR);
  _Float16* Cp = (_Float16*)(ws + 3 * ARR);
  double*  acc = (double*)(ws + 4 * ARR);
  float*   out = (float*)d_out;

  hipLaunchKernelGGL(prep_kernel, dim3(2 * HALFPTS / 256), dim3(256), 0, stream,
                     gts, preds, Qg, Cg, Qp, Cp, acc);
  hipLaunchKernelGGL(fused_kernel, dim3(NPTS / 32, NB), dim3(THREADS), 0, stream,
                     gts, preds, Qg, Cg, Qp, Cp, acc);
  hipLaunchKernelGGL(finalize_kernel, dim3(1), dim3(64), 0, stream, acc, out);
}

// Round 12
// 32.373 us; speedup vs baseline: 2.7679x; 1.0734x over previous
//
#include <hip/hip_runtime.h>
#include <hip/hip_bf16.h>
#include <hip/hip_fp16.h>

#define NB      8
#define NPTS    4096
#define KSEL    16
#define THREADS 384         // 6 waves: B,B,C,C,A,A
#define NSLOTS  64
#define HALFPTS (NB*NPTS)   // 32768 points per array

typedef _Float16 f16x8 __attribute__((ext_vector_type(8)));
typedef float    f32x16 __attribute__((ext_vector_type(16)));

__device__ __forceinline__ void ce(float& a, float& b) {
  const float lo = fminf(a, b), hi = fmaxf(a, b);
  a = lo; b = hi;
}
__device__ __forceinline__ float min3f(float a, float b, float c) {
  return fminf(fminf(a, b), c);              // fuses to v_min3_f32
}

// two sorted-2 -> sorted-4 (4 ce)
__device__ __forceinline__ void m22(float* o, const float* a, const float* b) {
  o[0]=a[0]; o[1]=a[1]; o[2]=b[1]; o[3]=b[0];
  ce(o[0],o[2]); ce(o[1],o[3]);
  ce(o[0],o[1]); ce(o[2],o[3]);
}
// two sorted-4 -> sorted-8 (12 ce)
__device__ __forceinline__ void m44(float* o, const float* a, const float* b) {
  o[0]=a[0]; o[1]=a[1]; o[2]=a[2]; o[3]=a[3];
  o[4]=b[3]; o[5]=b[2]; o[6]=b[1]; o[7]=b[0];
  ce(o[0],o[4]); ce(o[1],o[5]); ce(o[2],o[6]); ce(o[3],o[7]);
  ce(o[0],o[2]); ce(o[1],o[3]); ce(o[4],o[6]); ce(o[5],o[7]);
  ce(o[0],o[1]); ce(o[2],o[3]); ce(o[4],o[5]); ce(o[6],o[7]);
}
// two sorted-8 -> sorted-16 (32 ce)
__device__ __forceinline__ void m88(float* o, const float* a, const float* b) {
#pragma unroll
  for (int i = 0; i < 8; ++i) { o[i] = a[i]; o[15 - i] = b[i]; }
#pragma unroll
  for (int d = 8; d >= 1; d >>= 1)
#pragma unroll
    for (int i = 0; i < 16; ++i)
      if ((i & d) == 0) ce(o[i], o[i + d]);
}
// full sort of 16 unsorted values: f = sorted(h); h clobbered.
__device__ __forceinline__ void sort16(float* f, float* h) {
#pragma unroll
  for (int i = 0; i < 16; i += 2) ce(h[i], h[i + 1]);
  float s[16];
  m22(s + 0, h + 0, h + 2);  m22(s + 4,  h + 4,  h + 6);
  m22(s + 8, h + 8, h + 10); m22(s + 12, h + 12, h + 14);
  m44(h + 0, s + 0, s + 4);  m44(h + 8, s + 8, s + 12);
  m88(f, h + 0, h + 8);
}
// keep smallest-16 of two sorted-16 lists, in place in h.
__device__ __forceinline__ void keep16(float* h, const float* g) {
#pragma unroll
  for (int i = 0; i < KSEL; ++i) h[i] = fminf(h[i], g[KSEL - 1 - i]);
#pragma unroll
  for (int d = 8; d >= 1; d >>= 1)
#pragma unroll
    for (int i = 0; i < KSEL; ++i)
      if ((i & d) == 0) ce(h[i], h[i + d]);
}

// Per point: Q-role K-vector [xh,xh,xl, yh,yh,yl, zh,zh,zl, 1,1, 0...] and
// C-role [(-2x)h,(-2x)l,(-2x)h, ..., cnh,cnl, 0...]; dot(Q,C) = -2 q.c + |c|^2
// (~1e-6 abs error; f16 x f16 products are exact in f32 MFMA accumulation).
// Also zeroes the accumulator slots (block 0).
extern "C" __global__ __launch_bounds__(256)
void prep_kernel(const float* __restrict__ gts, const float* __restrict__ preds,
                 _Float16* __restrict__ Qg, _Float16* __restrict__ Cg,
                 _Float16* __restrict__ Qp, _Float16* __restrict__ Cp,
                 double* __restrict__ acc) {
  if (blockIdx.x == 0 && threadIdx.x < 3 * NSLOTS) acc[threadIdx.x] = 0.0;
  const int i = blockIdx.x * 256 + threadIdx.x;     // 0..2*HALFPTS-1
  const bool isg = i < HALFPTS;
  const float* __restrict__ src = isg ? gts : preds;
  const int j = isg ? i : i - HALFPTS;
  const float x = src[3*j], y = src[3*j+1], z = src[3*j+2];
  const float cn = fmaf(x, x, fmaf(y, y, z * z));

  const _Float16 xh = (_Float16)x, yh = (_Float16)y, zh = (_Float16)z;
  const _Float16 xl = (_Float16)(x - (float)xh);
  const _Float16 yl = (_Float16)(y - (float)yh);
  const _Float16 zl = (_Float16)(z - (float)zh);
  const float mx = -2.f*x, my = -2.f*y, mz = -2.f*z;
  const _Float16 mxh = (_Float16)mx, myh = (_Float16)my, mzh = (_Float16)mz;
  const _Float16 mxl = (_Float16)(mx - (float)mxh);
  const _Float16 myl = (_Float16)(my - (float)myh);
  const _Float16 mzl = (_Float16)(mz - (float)mzh);
  const _Float16 cnh = (_Float16)cn;
  const _Float16 cnl = (_Float16)(cn - (float)cnh);
  const _Float16 one = (_Float16)1.0f, zr = (_Float16)0.0f;

  _Float16* Q = (isg ? Qg : Qp) + (size_t)j * 16;
  _Float16* C = (isg ? Cg : Cp) + (size_t)j * 16;
  Q[0]=xh; Q[1]=xh; Q[2]=xl; Q[3]=yh; Q[4]=yh; Q[5]=yl;
  Q[6]=zh; Q[7]=zh; Q[8]=zl; Q[9]=one; Q[10]=one;
  Q[11]=zr; Q[12]=zr; Q[13]=zr; Q[14]=zr; Q[15]=zr;
  C[0]=mxh; C[1]=mxl; C[2]=mxh; C[3]=myh; C[4]=myl; C[5]=myh;
  C[6]=mzh; C[7]=mzl; C[8]=mzh; C[9]=cnh; C[10]=cnl;
  C[11]=zr; C[12]=zr; C[13]=zr; C[14]=zr; C[15]=zr;
}

// Block: 6 waves, one 32-query strip. role = w>>1 (0=B: gt-cand x gt-q top-k;
// 1=C: gt-cand x pred-q min; 2=A: pred-cand x gt-q top-k); sub = w&1 selects
// cand half [sub*2048, +2048) = 64 tiles. B/C share cand ranges (L1 reuse).
// Selection: h[16] per-row fmin (64 slices/query total). Merge: sort16 +
// cross-half shfl + ONE LDS level + exchange.
extern "C" __global__ __launch_bounds__(THREADS, 6)
void fused_kernel(const float* __restrict__ gts, const float* __restrict__ preds,
                  const _Float16* __restrict__ Qg, const _Float16* __restrict__ Cg,
                  const _Float16* __restrict__ Qp, const _Float16* __restrict__ Cp,
                  double* __restrict__ acc) {
  __shared__ float TQ[3][32][KSEL + 1];   // 0: B-sub1 in; 1: A-sub1 in; 2: A final
  __shared__ float TCm[2][32];

  const int t    = threadIdx.x;
  const int lane = t & 63;
  const int w    = t >> 6;          // 0..5
  const int col  = lane & 31;
  const int half = lane >> 5;
  const int b    = blockIdx.y;
  const int strip= blockIdx.x;
  const int role = w >> 1;          // 0=B, 1=C, 2=A
  const int sub  = w & 1;

  const size_t qoff = ((size_t)(b * NPTS + strip * 32 + col)) * 16 + half * 8;
  const f16x8 q = (role == 1) ? *(const f16x8*)(Qp + qoff) : *(const f16x8*)(Qg + qoff);

  const _Float16* __restrict__ cb =
      ((role == 2) ? Cp : Cg) + ((size_t)(b * NPTS + sub * 2048)) * 16;
  const _Float16* __restrict__ p = cb + (size_t)col * 16 + half * 8;

  f32x16 zz;
#pragma unroll
  for (int i = 0; i < 16; ++i) zz[i] = 0.f;

  float f[KSEL];                    // topk result (roles 0,2)
  float bw = 1e30f;                 // C result (role 1)

  if (role != 1) {
    float h[16];
#pragma unroll
    for (int i = 0; i < 16; ++i) h[i] = 1e30f;
#pragma unroll 2
    for (int tile = 0; tile < 64; ++tile) {
      const f16x8 at = *(const f16x8*)(p + (size_t)tile * 512);
      const f32x16 a = __builtin_amdgcn_mfma_f32_32x32x16_f16(at, q, zz, 0, 0, 0);
#pragma unroll
      for (int r = 0; r < 16; ++r) h[r] = fminf(h[r], a[r]);  // top-1 per row slice
    }
    sort16(f, h);
    float g[KSEL];
#pragma unroll
    for (int i = 0; i < KSEL; ++i) g[i] = __shfl_xor(f[i], 32);
    keep16(f, g);
    if (sub == 1 && half == 0) {    // export sub1 list (B->TQ[0], A->TQ[1])
      const int slot = (role == 0) ? 0 : 1;
#pragma unroll
      for (int i = 0; i < KSEL; ++i) TQ[slot][col][i] = f[i];
    }
  } else {
#pragma unroll 2
    for (int tile = 0; tile < 64; ++tile) {
      const f16x8 at = *(const f16x8*)(p + (size_t)tile * 512);
      const f32x16 a = __builtin_amdgcn_mfma_f32_32x32x16_f16(at, q, zz, 0, 0, 0);
      const float c0 = min3f(a[0],  a[1],  a[2]);
      const float c1 = min3f(a[3],  a[4],  a[5]);
      const float c2 = min3f(a[6],  a[7],  a[8]);
      const float c3 = min3f(a[9],  a[10], a[11]);
      const float c4 = min3f(a[12], a[13], a[14]);
      const float d0 = min3f(c0, c1, a[15]);
      const float d1 = min3f(c2, c3, c4);
      bw = min3f(bw, d0, d1);
    }
    bw = fminf(bw, __shfl_xor(bw, 32));
    if (half == 0) TCm[sub][col] = bw;
  }
  __syncthreads();

  // phase 2: finals. B-final in w0's f; A-final merged in w4 then exported;
  // C-final computed by w2 then exported.
  if (w == 0) {
    float g[KSEL];
#pragma unroll
    for (int i = 0; i < KSEL; ++i) g[i] = TQ[0][col][i];
    keep16(f, g);
  }
  if (w == 4) {
    float g[KSEL];
#pragma unroll
    for (int i = 0; i < KSEL; ++i) g[i] = TQ[1][col][i];
    keep16(f, g);
    if (half == 0) {
#pragma unroll
      for (int i = 0; i < KSEL; ++i) TQ[2][col][i] = f[i];
    }
  }
  if (w == 2) {
    const float bwf = fminf(TCm[0][col], TCm[1][col]);
    if (half == 0) TCm[0][col] = bwf;
  }
  __syncthreads();

  // phase 3: epilogue in w0 (holds B-final = val_2 list)
  if (w == 0) {
    float f1[KSEL];
#pragma unroll
    for (int i = 0; i < KSEL; ++i) f1[i] = TQ[2][col][i];   // A-final = val_1 list
    const float bwf = TCm[0][col];

    const float* gq = gts   + ((size_t)(b * NPTS) + strip * 32 + col) * 3;
    const float qn = fmaf(gq[0], gq[0], fmaf(gq[1], gq[1], gq[2] * gq[2]));
    const float* pq = preds + ((size_t)(b * NPTS) + strip * 32 + col) * 3;
    const float pn = fmaf(pq[0], pq[0], fmaf(pq[1], pq[1], pq[2] * pq[2]));

    float v1 = bwf + pn;          // loss_1 term (pred query)
    float v2 = f1[0] + qn;        // loss_2 term (gt query)
    float v3 = 0.0f;              // density: (val_1 - val_2)^2, qn cancels
#pragma unroll
    for (int i = 0; i < KSEL; ++i) {
      const float df = f1[i] - f[i];
      v3 = fmaf(df, df, v3);
    }
    if (half) { v1 = 0.f; v2 = 0.f; v3 = 0.f; }   // halves hold duplicates
#pragma unroll
    for (int off = 32; off >= 1; off >>= 1) {
      v1 += __shfl_xor(v1, off);
      v2 += __shfl_xor(v2, off);
      v3 += __shfl_xor(v3, off);
    }
    if (lane == 0) {
      const int slot = (strip + 13 * b) & (NSLOTS - 1);
      atomicAdd(&acc[0 * NSLOTS + slot], (double)v1);
      atomicAdd(&acc[1 * NSLOTS + slot], (double)v2);
      atomicAdd(&acc[2 * NSLOTS + slot], (double)v3);
    }
  }
}

extern "C" __global__ void finalize_kernel(const double* __restrict__ acc,
                                           float* __restrict__ out) {
  const int l = threadIdx.x;  // 64 threads
  double a = acc[l], b = acc[NSLOTS + l], c = acc[2 * NSLOTS + l];
#pragma unroll
  for (int off = 32; off >= 1; off >>= 1) {
    a += __shfl_xor(a, off);
    b += __shfl_xor(b, off);
    c += __shfl_xor(c, off);
  }
  if (l == 0) {
    const double loss1 = a / (double)((size_t)NB * NPTS);
    const double loss2 = b / (double)((size_t)NB * NPTS);
    const double dens  = c / (double)((size_t)NB * NPTS * KSEL);
    out[0] = (float)(loss1 + loss2);
    out[1] = (float)dens;
  }
}

extern "C" void kernel_launch(void* const* d_in, const int* in_sizes, int n_in,
                              void* d_out, int out_size, void* d_ws, size_t ws_size,
                              hipStream_t stream) {
  const float* gts   = (const float*)d_in[0];
  const float* preds = (const float*)d_in[1];
  char* ws = (char*)d_ws;
  const size_t ARR = (size_t)HALFPTS * 16 * sizeof(_Float16);   // 1 MiB each
  _Float16* Qg = (_Float16*)(ws + 0 * ARR);
  _Float16* Cg = (_Float16*)(ws + 1 * ARR);
  _Float16* Qp = (_Float16*)(ws + 2 * ARR);
  _Float16* Cp = (_Float16*)(ws + 3 * ARR);
  double*  acc = (double*)(ws + 4 * ARR);
  float*   out = (float*)d_out;

  hipLaunchKernelGGL(prep_kernel, dim3(2 * HALFPTS / 256), dim3(256), 0, stream,
                     gts, preds, Qg, Cg, Qp, Cp, acc);
  hipLaunchKernelGGL(fused_kernel, dim3(NPTS / 32, NB), dim3(THREADS), 0, stream,
                     gts, preds, Qg, Cg, Qp, Cp, acc);
  hipLaunchKernelGGL(finalize_kernel, dim3(1), dim3(64), 0, stream, acc, out);
}